// Round 11
// baseline (94.324 us; speedup 1.0000x reference)
//
#include <hip/hip_runtime.h>
#include <hip/hip_bf16.h>
#include <stdint.h>

#define NROWS 8192
#define DIM 512

typedef int   i32x4 __attribute__((ext_vector_type(4)));
typedef int   i32x8 __attribute__((ext_vector_type(8)));
typedef float f32x4 __attribute__((ext_vector_type(4)));

__device__ __forceinline__ void gload16(const unsigned char* g, unsigned char* l) {
    __builtin_amdgcn_global_load_lds((const __attribute__((address_space(1))) void*)g,
                                     (__attribute__((address_space(3))) void*)l,
                                     16, 0, 0);
}

// ---------------- Kernel 1: L2-normalize rows -> fp8 e4m3; zero d_out ----------------
__global__ __launch_bounds__(256) void knorm(const float* __restrict__ in,
                                             unsigned char* __restrict__ out,
                                             float* __restrict__ loss_out) {
    if (blockIdx.x == 0 && threadIdx.x == 0) loss_out[0] = 0.0f;
    const int row  = (blockIdx.x << 2) + (threadIdx.x >> 6);
    const int lane = threadIdx.x & 63;
    const float4* src = (const float4*)(in + (size_t)row * DIM);
    float4 a = src[lane];
    float4 b = src[lane + 64];
    float ss = a.x*a.x + a.y*a.y + a.z*a.z + a.w*a.w
             + b.x*b.x + b.y*b.y + b.z*b.z + b.w*b.w;
    #pragma unroll
    for (int m = 1; m < 64; m <<= 1) ss += __shfl_xor(ss, m);
    const float inv = 1.0f / sqrtf(ss);
    int* dst = (int*)(out + (size_t)row * DIM);
    int p0 = __builtin_amdgcn_cvt_pk_fp8_f32(a.x*inv, a.y*inv, 0, false);
    p0     = __builtin_amdgcn_cvt_pk_fp8_f32(a.z*inv, a.w*inv, p0, true);
    int p1 = __builtin_amdgcn_cvt_pk_fp8_f32(b.x*inv, b.y*inv, 0, false);
    p1     = __builtin_amdgcn_cvt_pk_fp8_f32(b.z*inv, b.w*inv, p1, true);
    dst[lane]      = p0;
    dst[lane + 64] = p1;
}

// ---------------- Kernel 2: MX-fp8 (unit-scale) upper-triangle E*E^T ----------------
// 256x256 tile, 16 waves (4x4, each 64x64), BK=128 (K=512 -> only 4 K-steps:
// 4 barrier convoys instead of 16 -- the measured m233-style 2-phase overhead
// amortizes 4x). mfma_scale_f32_16x16x128_f8f6f4 (fmt 0 = e4m3, scales =
// 0x7F = 2^0): 16 MFMA/wave/K-step, each K=128. Staged bytes per step per
// operand unchanged (256 rows x 128 B = 32 KB); LDS = 2 bufs x 2 ops x 32 KB
// = 128 KB. Counted vmcnt(4) dbuf schedule (R5-proven). Swizzle: rows are
// 128 B = 8 16B-groups; stored(r,g) = data(r, g ^ (r&7)); linear gload_lds
// dest + inverse-swizzled source + XOR'd ds_read. Lanes of a quarter-wave
// cover all 8 groups -> 2 lanes/slot = free. k-mapping is identical for A/B
// fragments (both depend only on lane id), so the dot is robust to any
// per-lane k-permutation assumption. Atomic-free partials epilogue (R9).
__global__ __launch_bounds__(1024, 1) void kgemm(const unsigned char* __restrict__ E,
                                                 float* __restrict__ part,
                                                 float* __restrict__ pospart) {
    __shared__ unsigned char lds[2][2][256 * 128];   // [buf][A/B][256 rows x 128 B]

    const int tid = threadIdx.x;
    const int w = tid >> 6;
    const int l = tid & 63;

    // ---- block id -> (bi, bj): supertile triangle decode ----
    const int lin = (int)((blockIdx.x & 7) * 66 + (blockIdx.x >> 3));
    int rem = lin;
    int SI = -1, SJ = -1;
    #pragma unroll
    for (int s = 0; s < 10; s++) {
        constexpr int si_t[10] = {0,0,0,0,1,1,1,2,2,3};
        constexpr int sj_t[10] = {0,1,2,3,1,2,3,2,3,3};
        const int sz = (si_t[s] == sj_t[s]) ? 36 : 64;
        if (SI < 0) {
            if (rem < sz) { SI = si_t[s]; SJ = sj_t[s]; }
            else rem -= sz;
        }
    }
    int bi, bj;
    if (SI == SJ) {
        int x = 0;
        while (rem >= 8 - x) { rem -= 8 - x; x++; }
        bi = (SI << 3) + x; bj = (SI << 3) + x + rem;
    } else {
        bi = (SI << 3) + (rem >> 3);
        bj = (SJ << 3) + (rem & 7);
    }

    const int brow = bi << 8;
    const int bcol = bj << 8;
    const int wr = (w >> 2) << 6;
    const int wc = (w & 3) << 6;

    f32x4 acc[4][4];
    #pragma unroll
    for (int i = 0; i < 4; i++)
        #pragma unroll
        for (int j = 0; j < 4; j++) acc[i][j] = (f32x4)0.0f;

    // staging: sweep q covers rows q*128 + w*8 + (l>>3); group g = l&7.
    // dest linear byte = q*16384 + w*1024 + l*16 (wave-uniform base + l*16).
    const int g_src = ((l & 7) ^ ((l >> 3) & 7)) << 4;   // inverse-swizzled source byte
    const int r_st  = (w << 3) + (l >> 3);               // row within sweep

    auto STAGE = [&](int buf, int kt) {
        const size_t cb = (size_t)(kt << 7) + g_src;
        #pragma unroll
        for (int q = 0; q < 2; q++) {
            const int r = (q << 7) + r_st;
            gload16(E + (size_t)(brow + r) * DIM + cb, &lds[buf][0][(q << 14) + (w << 10)]);
            gload16(E + (size_t)(bcol + r) * DIM + cb, &lds[buf][1][(q << 14) + (w << 10)]);
        }
    };

    // ds_read: lane wants data groups 2h, 2h+1 (h = l>>4) of its rows;
    // stored at g ^ (r&7), r&7 == l&7 (row bases are multiples of 16).
    const int go0 = ((((l >> 4) << 1)    ) ^ (l & 7)) << 4;
    const int go1 = ((((l >> 4) << 1) | 1) ^ (l & 7)) << 4;

    auto COMPUTE = [&](int buf) {
        const unsigned char* sA = lds[buf][0];
        const unsigned char* sB = lds[buf][1];
        i32x8 bF[4];
        #pragma unroll
        for (int ni = 0; ni < 4; ni++) {
            const int rB = (wc + (ni << 4) + (l & 15)) << 7;
            i32x4 lo = *(const i32x4*)&sB[rB + go0];
            i32x4 hi = *(const i32x4*)&sB[rB + go1];
            bF[ni][0]=lo[0]; bF[ni][1]=lo[1]; bF[ni][2]=lo[2]; bF[ni][3]=lo[3];
            bF[ni][4]=hi[0]; bF[ni][5]=hi[1]; bF[ni][6]=hi[2]; bF[ni][7]=hi[3];
        }
        #pragma unroll
        for (int mi = 0; mi < 4; mi++) {
            const int rA = (wr + (mi << 4) + (l & 15)) << 7;
            i32x4 lo = *(const i32x4*)&sA[rA + go0];
            i32x4 hi = *(const i32x4*)&sA[rA + go1];
            i32x8 aF;
            aF[0]=lo[0]; aF[1]=lo[1]; aF[2]=lo[2]; aF[3]=lo[3];
            aF[4]=hi[0]; aF[5]=hi[1]; aF[6]=hi[2]; aF[7]=hi[3];
            #pragma unroll
            for (int ni = 0; ni < 4; ni++)
                acc[mi][ni] = __builtin_amdgcn_mfma_scale_f32_16x16x128_f8f6f4(
                    aF, bF[ni], acc[mi][ni], 0, 0,           // fmtA=fp8, fmtB=fp8
                    0, 0x7F7F7F7F, 0, 0x7F7F7F7F);           // unit scales (2^0)
        }
    };

    STAGE(0, 0);
    #pragma unroll
    for (int kt = 0; kt < 4; kt++) {
        if (kt > 0) __builtin_amdgcn_s_barrier();
        if (kt < 3) {
            STAGE((kt + 1) & 1, kt + 1);
            asm volatile("s_waitcnt vmcnt(4)" ::: "memory");
        } else {
            asm volatile("s_waitcnt vmcnt(0)" ::: "memory");
        }
        __builtin_amdgcn_sched_barrier(0);
        __builtin_amdgcn_s_barrier();
        COMPUTE(kt & 1);
    }

    // ---- epilogue: exp(10*dot - 10), classify, LDS assemble, streaming store ----
    float* lds_row = (float*)&lds[0][0][0];       // [4][256]
    float* lds_col = lds_row + 1024;              // [4][256]
    float* lds_pos = lds_row + 2048;              // [4][256]

    __syncthreads();   // all COMPUTE reads done before LDS reuse

    if (bi == bj) {
        #pragma unroll
        for (int mi = 0; mi < 4; mi++) {
            #pragma unroll
            for (int r = 0; r < 4; r++) {
                const int lrow = wr + (mi << 4) + ((l >> 4) << 2) + r;
                const int gi = brow + lrow;
                float p = 0.0f, n = 0.0f;
                #pragma unroll
                for (int ni = 0; ni < 4; ni++) {
                    const int gj = bcol + wc + (ni << 4) + (l & 15);
                    const float e = __expf(fmaf(acc[mi][ni][r], 10.0f, -10.0f));
                    if (gi == gj) {
                    } else if ((gi >> 2) == (gj >> 2)) {
                        p += e;
                    } else {
                        n += e;
                    }
                }
                #pragma unroll
                for (int m = 1; m < 16; m <<= 1) {
                    n += __shfl_xor(n, m);
                    p += __shfl_xor(p, m);
                }
                if ((l & 15) == 0) {
                    lds_row[((w & 3) << 8) + lrow] = n;
                    lds_pos[((w & 3) << 8) + lrow] = p;
                }
            }
        }
    } else {
        float c[4] = {0.0f, 0.0f, 0.0f, 0.0f};
        #pragma unroll
        for (int mi = 0; mi < 4; mi++) {
            #pragma unroll
            for (int r = 0; r < 4; r++) {
                const int lrow = wr + (mi << 4) + ((l >> 4) << 2) + r;
                float n = 0.0f;
                #pragma unroll
                for (int ni = 0; ni < 4; ni++) {
                    const float e = __expf(fmaf(acc[mi][ni][r], 10.0f, -10.0f));
                    n += e;
                    c[ni] += e;
                }
                #pragma unroll
                for (int m = 1; m < 16; m <<= 1) n += __shfl_xor(n, m);
                if ((l & 15) == 0) lds_row[((w & 3) << 8) + lrow] = n;
            }
        }
        #pragma unroll
        for (int ni = 0; ni < 4; ni++) {
            c[ni] += __shfl_xor(c[ni], 16);
            c[ni] += __shfl_xor(c[ni], 32);
            if ((l >> 4) == 0)
                lds_col[((w >> 2) << 8) + wc + (ni << 4) + l] = c[ni];
        }
    }
    __syncthreads();

    if (tid < 256) {
        const float s = lds_row[tid] + lds_row[256 + tid]
                      + lds_row[512 + tid] + lds_row[768 + tid];
        part[((size_t)lin << 9) + tid] = s;
    } else if (tid < 512) {
        if (bi != bj) {
            const int cc = tid - 256;
            const float s = lds_col[cc] + lds_col[256 + cc]
                          + lds_col[512 + cc] + lds_col[768 + cc];
            part[((size_t)lin << 9) + 256 + cc] = s;
        }
    } else if (tid < 768) {
        if (bi == bj) {
            const int rr = tid - 512;
            const float s = lds_pos[rr] + lds_pos[256 + rr]
                          + lds_pos[512 + rr] + lds_pos[768 + rr];
            pospart[(bi << 8) + rr] = s;
        }
    }
}

// ---------------- Kernel 3: gather partials, compute loss, reduce ----------------
__global__ __launch_bounds__(256) void kred(const float* __restrict__ part,
                                            const float* __restrict__ pospart,
                                            float* __restrict__ out) {
    const int T = blockIdx.x;
    const int r = threadIdx.x;

    auto linof = [](int a, int b) {   // a <= b, 0..31
        constexpr int base[4][4] = {{0, 36, 100, 164},
                                    {0, 228, 264, 328},
                                    {0, 0, 392, 428},
                                    {0, 0, 0, 492}};
        const int SI = a >> 3, SJ = b >> 3, x = a & 7, y = b & 7;
        int inner;
        if (SI == SJ) inner = (x << 3) - ((x * (x - 1)) >> 1) + (y - x);
        else          inner = (x << 3) + y;
        return base[SI][SJ] + inner;
    };

    float n = 0.0f;
    for (int bj = T; bj < 32; bj++)
        n += part[((size_t)linof(T, bj) << 9) + r];
    for (int bi = 0; bi < T; bi++)
        n += part[((size_t)linof(bi, T) << 9) + 256 + r];
    const float p = pospart[(T << 8) + r];

    float s = __logf(p + n + 1e-8f) - __logf(p);
    #pragma unroll
    for (int m = 1; m < 64; m <<= 1) s += __shfl_xor(s, m);
    __shared__ float red[4];
    if ((r & 63) == 0) red[r >> 6] = s;
    __syncthreads();
    if (r == 0)
        atomicAdd(out, (red[0] + red[1] + red[2] + red[3]) * (1.0f / (float)NROWS));
}

extern "C" void kernel_launch(void* const* d_in, const int* in_sizes, int n_in,
                              void* d_out, int out_size, void* d_ws, size_t ws_size,
                              hipStream_t stream) {
    (void)in_sizes; (void)n_in; (void)out_size; (void)ws_size;
    const float* emb = (const float*)d_in[0];
    unsigned char* E8 = (unsigned char*)d_ws;                            // 4 MB fp8
    float* pospart = (float*)((char*)d_ws + (size_t)NROWS * DIM);        // 32 KB
    float* part    = pospart + 32 * 256;                                 // 1.08 MB

    knorm<<<NROWS / 4, 256, 0, stream>>>(emb, E8, (float*)d_out);
    kgemm<<<528, 1024, 0, stream>>>(E8, part, pospart);
    kred<<<32, 256, 0, stream>>>(part, pospart, (float*)d_out);
}